// Round 17
// baseline (796.571 us; speedup 1.0000x reference)
//
#include <hip/hip_runtime.h>

#define BB 2
#define NN 4096
#define NP 1024
#define MM 32
#define CC 35
#define CIN 32
#define WGRID 256   // 2 producers + 254 workers; 1 block/CU -> producers get DEDICATED CUs

typedef float f2 __attribute__((ext_vector_type(2)));

// key-only DPP max-combine (u64 key = dist_bits<<32 | ~idx)
#define KEY_DPP(CTRL) do { \
    int _lo = (int)(unsigned)key, _hi = (int)(unsigned)(key >> 32); \
    int _olo = __builtin_amdgcn_mov_dpp(_lo, CTRL, 0xF, 0xF, true); \
    int _ohi = __builtin_amdgcn_mov_dpp(_hi, CTRL, 0xF, 0xF, true); \
    unsigned long long _ok = ((unsigned long long)(unsigned)_ohi << 32) | (unsigned)_olo; \
    if (_ok > key) key = _ok; \
} while (0)

// ---------------- prep: zero progress + pack MLP weights [c4][o][4] ----------------
__global__ void prep_kernel(const float* __restrict__ w1, const float* __restrict__ w2,
                            const float* __restrict__ w3,
                            float* __restrict__ w1p, float* __restrict__ w2p,
                            float* __restrict__ w3p, int* __restrict__ progress)
{
    int g = blockIdx.x * 256 + threadIdx.x;
    int stride = gridDim.x * 256;
    if (g < 2) progress[g] = 0;
    for (int i = g; i < 9 * 64 * 4; i += stride) {
        int c4 = i >> 8, o = (i >> 2) & 63, cl = i & 3;
        int c = 4 * c4 + cl;
        w1p[i] = (c < CC) ? w1[o * CC + c] : 0.0f;
    }
    for (int i = g; i < 16 * 64 * 4; i += stride) {
        int c4 = i >> 8, o = (i >> 2) & 63, cl = i & 3;
        w2p[i] = w2[o * 64 + 4 * c4 + cl];
    }
    for (int i = g; i < 16 * 128 * 4; i += stride) {
        int c4 = i >> 9, o = (i >> 2) & 127, cl = i & 3;
        w3p[i] = w3[o * 64 + 4 * c4 + cl];
    }
}

// ---------------- mega: fps producers (blocks 0..1) + knnafa workers ----------------
// Grid 256 = CU count: every block gets its own CU (round-robin dispatch),
// so worker compute cannot steal producer issue slots (R16's 563->800
// regression). Deadlock-safe even under adversarial placement: 256 blocks
// x 66KB LDS / 8 waves all fit co-resident regardless of packing.
union MegaSmem {
    struct {
        float4 pc[NN];                         // coord table for far-lookup (64KB)
        unsigned long long red[2][16];         // double-buffered row winners
    } f;
    struct {
        union {
            struct {
                unsigned kxs[NN];
                int hist[256];
                int wsum[4];
                unsigned long long blist[512];
            } k;
            struct {
                float xs_t[MM][36];
                float u[MM][20];
                float nfs[CC + 1][MM];
                float h1s[64][36];
                float h2s[64][36];
                float pmax[128][2];
            } a;
        };
        int idxs[MM];
        int scal[4];
        float qs[3];                           // this pair's newxyz (agent-coherent copy)
    } w;
};

__launch_bounds__(256, 2)
__global__ void mega_kernel(const float* __restrict__ xyz, const float* __restrict__ feat,
                            float* __restrict__ newxyz,
                            const float* __restrict__ aw1, const float* __restrict__ ab1,
                            const float* __restrict__ aw2, const float* __restrict__ ab2,
                            const float* __restrict__ aww, const float* __restrict__ abw,
                            const float* __restrict__ w1p, const float* __restrict__ b1,
                            const float* __restrict__ w2p, const float* __restrict__ b2,
                            const float* __restrict__ w3p, const float* __restrict__ b3,
                            float* __restrict__ out, int* __restrict__ progress)
{
    __shared__ MegaSmem S;
    const int t = threadIdx.x;

    if (blockIdx.x < BB) {
        // ================= FPS producer (frozen R12 loop) =================
#pragma clang fp contract(off)
        const int b = blockIdx.x;
        const float* xb = xyz + b * NN * 3;

        f2 px[8], py[8], pz[8], dist[8];
#pragma unroll
        for (int k = 0; k < 16; ++k) {
            int n = t + 256 * k;
            float x = xb[n * 3 + 0];
            float y = xb[n * 3 + 1];
            float z = xb[n * 3 + 2];
            px[k >> 1][k & 1] = x;
            py[k >> 1][k & 1] = y;
            pz[k >> 1][k & 1] = z;
            dist[k >> 1][k & 1] = 1e10f;
            S.f.pc[n] = make_float4(x, y, z, 0.0f);
        }
        __syncthreads();

        int far = 0;
        for (int s = 0; s < NP; ++s) {
            float4 c = S.f.pc[far];            // uniform LDS broadcast
            if (t == 0) {
                // agent-coherent publish (visible cross-XCD at MALL)
                __hip_atomic_store(&newxyz[(b * NP + s) * 3 + 0], c.x,
                                   __ATOMIC_RELAXED, __HIP_MEMORY_SCOPE_AGENT);
                __hip_atomic_store(&newxyz[(b * NP + s) * 3 + 1], c.y,
                                   __ATOMIC_RELAXED, __HIP_MEMORY_SCOPE_AGENT);
                __hip_atomic_store(&newxyz[(b * NP + s) * 3 + 2], c.z,
                                   __ATOMIC_RELAXED, __HIP_MEMORY_SCOPE_AGENT);
            }
            const f2 cx = { c.x, c.x }, cy = { c.y, c.y }, cz = { c.z, c.z };

            float bv = -1.0f; int bi = 0;
#pragma unroll
            for (int j = 0; j < 8; ++j) {
                f2 dx = px[j] - cx, dy = py[j] - cy, dz = pz[j] - cz;
                f2 d = (dx * dx + dy * dy) + dz * dz;
                f2 dd = __builtin_elementwise_min(dist[j], d);
                dist[j] = dd;
                if (dd.x > bv) { bv = dd.x; bi = t + 256 * (2 * j); }
                if (dd.y > bv) { bv = dd.y; bi = t + 256 * (2 * j + 1); }
            }

            unsigned long long key =
                ((unsigned long long)(unsigned)__float_as_int(bv) << 32)
                | (unsigned)(0xFFFFFFFFu - (unsigned)bi);

            KEY_DPP(0xB1);
            KEY_DPP(0x4E);
            KEY_DPP(0x141);
            KEY_DPP(0x140);

            const int buf = s & 1;
            if ((t & 15) == 0) S.f.red[buf][t >> 4] = key;
            __syncthreads();

            key = S.f.red[buf][t & 15];
            KEY_DPP(0xB1);
            KEY_DPP(0x4E);
            KEY_DPP(0x141);
            KEY_DPP(0x140);
            far = (int)(0xFFFFFFFFu - (unsigned)key);

            // release flag: orders all prior newxyz stores before it
            if (t == 0 && (s & 15) == 15)
                __hip_atomic_store(&progress[b], s + 1, __ATOMIC_RELEASE,
                                   __HIP_MEMORY_SCOPE_AGENT);
        }
        return;
    }

    // ================= workers: grid-stride over (b,p) pairs =================
    for (int pair = blockIdx.x - BB; pair < BB * NP; pair += WGRID - BB) {
        const int p = pair >> 1, b = pair & 1;
        const int bp = b * NP + p;

        // wait until fps has published newxyz[b][p]; fetch it coherently
        if (t == 0) {
            while (__hip_atomic_load(&progress[b], __ATOMIC_RELAXED,
                                     __HIP_MEMORY_SCOPE_AGENT) <= p)
                __builtin_amdgcn_s_sleep(64);
            (void)__hip_atomic_load(&progress[b], __ATOMIC_ACQUIRE,
                                    __HIP_MEMORY_SCOPE_AGENT);
            S.w.qs[0] = __hip_atomic_load(&newxyz[bp * 3 + 0], __ATOMIC_RELAXED,
                                          __HIP_MEMORY_SCOPE_AGENT);
            S.w.qs[1] = __hip_atomic_load(&newxyz[bp * 3 + 1], __ATOMIC_RELAXED,
                                          __HIP_MEMORY_SCOPE_AGENT);
            S.w.qs[2] = __hip_atomic_load(&newxyz[bp * 3 + 2], __ATOMIC_RELAXED,
                                          __HIP_MEMORY_SCOPE_AGENT);
        }
        __syncthreads();

        // ---- kNN phase (radix-select; exact: contract off) ----
        {
#pragma clang fp contract(off)
            const float* xb = xyz + b * NN * 3;
            const float qx = S.w.qs[0];
            const float qy = S.w.qs[1];
            const float qz = S.w.qs[2];
            const float qn = (qx * qx + qy * qy) + qz * qz;

            S.w.k.hist[t] = 0;
            if (t < 4) S.w.scal[t] = 0;
            __syncthreads();

#pragma unroll
            for (int k = 0; k < 16; ++k) {
                int n = t + 256 * k;
                float x = xb[n * 3 + 0], y = xb[n * 3 + 1], z = xb[n * 3 + 2];
                float xn = (x * x + y * y) + z * z;
                float dt = (qx * x + qy * y) + qz * z;
                float d = (qn + xn) - 2.0f * dt;
                unsigned bits = __float_as_uint(d);
                unsigned kx = bits ^ ((unsigned)((int)bits >> 31) | 0x80000000u);
                S.w.k.kxs[n] = kx;
                atomicAdd(&S.w.k.hist[kx >> 24], 1);
            }
            __syncthreads();

            {   // prefix over 256 buckets; locate boundary bucket
                int c = S.w.k.hist[t];
                int incl = c;
                const int lane = t & 63, w = t >> 6;
#pragma unroll
                for (int off = 1; off < 64; off <<= 1) {
                    int o = __shfl_up(incl, off);
                    if (lane >= off) incl += o;
                }
                if (lane == 63) S.w.k.wsum[w] = incl;
                __syncthreads();
                int base = 0;
                for (int ww = 0; ww < 4; ++ww) if (ww < w) base += S.w.k.wsum[ww];
                int excl = base + incl - c;
                if (excl < MM && MM <= excl + c) { S.w.scal[0] = t; S.w.scal[1] = excl; }
            }
            __syncthreads();

            const int B = S.w.scal[0];
            const int cntBelow = S.w.scal[1];
            const unsigned bstart = (unsigned)B << 24;

#pragma unroll
            for (int k = 0; k < 16; ++k) {
                int n = t + 256 * k;
                unsigned kx = S.w.k.kxs[n];
                if (kx < bstart) {
                    int pos = atomicAdd(&S.w.scal[3], 1);
                    S.w.idxs[pos] = n;
                } else if ((kx >> 24) == (unsigned)B) {
                    int pos = atomicAdd(&S.w.scal[2], 1);
                    if (pos < 512) S.w.k.blist[pos] = ((unsigned long long)kx << 32) | (unsigned)n;
                }
            }
            __syncthreads();

            const int nB = S.w.scal[2];
            const int k2 = MM - cntBelow;

            if (nB <= 512) {
                for (int m = t; m < nB; m += 256) {
                    unsigned long long my = S.w.k.blist[m];
                    int rank = 0;
                    for (int q = 0; q < nB; ++q) rank += (S.w.k.blist[q] < my) ? 1 : 0;
                    if (rank < k2)
                        S.w.idxs[cntBelow + rank] = (int)(my & 0xFFFFFFFFu);
                }
            } else {
                for (int r = 0; r < MM; ++r) {
                    unsigned bvk = 0xFFFFFFFFu; int bi = NN;
#pragma unroll
                    for (int k = 0; k < 16; ++k) {
                        int n = t + 256 * k;
                        unsigned v = S.w.k.kxs[n];
                        if (v < bvk) { bvk = v; bi = n; }
                    }
#pragma unroll
                    for (int off = 1; off < 64; off <<= 1) {
                        unsigned ov = __shfl_xor(bvk, off);
                        int   oi = __shfl_xor(bi, off);
                        if (ov < bvk || (ov == bvk && oi < bi)) { bvk = ov; bi = oi; }
                    }
                    if ((t & 63) == 0) { S.w.k.hist[t >> 6] = (int)bvk; S.w.k.wsum[t >> 6] = bi; }
                    __syncthreads();
                    unsigned fv = (unsigned)S.w.k.hist[0]; int fi = S.w.k.wsum[0];
#pragma unroll
                    for (int w = 1; w < 4; ++w) {
                        unsigned ov = (unsigned)S.w.k.hist[w]; int oi = S.w.k.wsum[w];
                        if (ov < fv || (ov == fv && oi < fi)) { fv = ov; fi = oi; }
                    }
                    if (t == 0) { S.w.idxs[r] = fi; S.w.k.kxs[fi] = 0xFFFFFFFFu; }
                    __syncthreads();
                }
            }
        }
        __syncthreads();   // knn buffers dead; afa buffers live

        // ---- gather x = concat(gxyz, gfeat) as [m][c] ----
        {
            const int m = t & 31, c0 = t >> 5;
            const int id = S.w.idxs[m] & (NN - 1);
            for (int c = c0; c < CC; c += 8) {
                float v;
                if (c < 3) v = xyz[(b * NN + id) * 3 + c] - S.w.qs[c];
                else       v = feat[(b * CIN + (c - 3)) * NN + id];
                S.w.a.xs_t[m][c] = v;
            }
            if (c0 == 0) S.w.a.xs_t[m][35] = 0.0f;
        }
        __syncthreads();

        const int i = t >> 3, jg = t & 7;

        float xi[36];
        {
            const float4* xp = (const float4*)&S.w.a.xs_t[i][0];
#pragma unroll
            for (int q = 0; q < 9; ++q) {
                float4 v = xp[q];
                xi[4 * q] = v.x; xi[4 * q + 1] = v.y; xi[4 * q + 2] = v.z; xi[4 * q + 3] = v.w;
            }
        }

        // phase A (u-split): thread (i,jg) computes o = 2jg, 2jg+1
#pragma unroll
        for (int oo = 0; oo < 2; ++oo) {
            const int o = 2 * jg + oo;
            float acc = 0.0f;
#pragma unroll
            for (int c = 0; c < CC; ++c) acc += aw1[o * CC + c] * xi[c];
            S.w.a.u[i][o] = acc;
        }
        __syncthreads();

        float ui[16];
        {
            const float4* up = (const float4*)&S.w.a.u[i][0];
#pragma unroll
            for (int q = 0; q < 4; ++q) {
                float4 v = up[q];
                ui[4 * q] = v.x; ui[4 * q + 1] = v.y; ui[4 * q + 2] = v.z; ui[4 * q + 3] = v.w;
            }
        }

        // phase B: per pair (i, j = jg+8*jk)
        float afa[CC];
#pragma unroll
        for (int c = 0; c < CC; ++c) afa[c] = 0.0f;

#pragma unroll
        for (int jk = 0; jk < 4; ++jk) {
            const int j = jg + 8 * jk;
            const bool diag = (i == j);

            float uj[16];
            {
                const float4* up = (const float4*)&S.w.a.u[j][0];
#pragma unroll
                for (int q = 0; q < 4; ++q) {
                    float4 v = up[q];
                    uj[4 * q] = v.x; uj[4 * q + 1] = v.y; uj[4 * q + 2] = v.z; uj[4 * q + 3] = v.w;
                }
            }

            float h1[16];
#pragma unroll
            for (int o = 0; o < 16; ++o) {
                float sv = ui[o] - uj[o];
                if (diag) sv += ui[o];
                h1[o] = fmaxf(sv + ab1[o], 0.0f);
            }

            float xj[36];
            {
                const float4* xp = (const float4*)&S.w.a.xs_t[j][0];
#pragma unroll
                for (int q = 0; q < 9; ++q) {
                    float4 v = xp[q];
                    xj[4 * q] = v.x; xj[4 * q + 1] = v.y; xj[4 * q + 2] = v.z; xj[4 * q + 3] = v.w;
                }
            }

            float h2[16];
#pragma unroll
            for (int o = 0; o < 16; ++o) {
                float acc = ab2[o];
#pragma unroll
                for (int c = 0; c < 16; ++c) acc += aw2[o * 16 + c] * h1[c];
                h2[o] = fmaxf(acc, 0.0f);
            }

#pragma unroll
            for (int c = 0; c < CC; ++c) {
                float acc = abw[c];
#pragma unroll
                for (int k = 0; k < 16; ++k) acc += aww[c * 16 + k] * h2[k];
                float pc_ = xi[c] - xj[c];
                if (diag) pc_ += xi[c];
                afa[c] += pc_ * acc;
            }
        }

#pragma unroll
        for (int c = 0; c < CC; ++c) {
            float v = afa[c];
            v += __shfl_xor(v, 1);
            v += __shfl_xor(v, 2);
            v += __shfl_xor(v, 4);
            if (jg == 0) S.w.a.nfs[c][i] = xi[c] + v;
        }
        if (jg == 0) S.w.a.nfs[35][i] = 0.0f;
        __syncthreads();

        // MLP layer 1: 35 -> 64 (packed w1p; c=35 pad term exactly 0)
        {
            const int o = t & 63, ib = (t >> 6) << 3;
            float acc[8];
            float bb = b1[o];
#pragma unroll
            for (int k = 0; k < 8; ++k) acc[k] = bb;
            const float4* wp = (const float4*)w1p;
#pragma unroll
            for (int c4 = 0; c4 < 9; ++c4) {
                float4 w = wp[c4 * 64 + o];
#pragma unroll
                for (int cl = 0; cl < 4; ++cl) {
                    const int c = 4 * c4 + cl;
                    float wc = ((const float*)&w)[cl];
                    const float4* np4 = (const float4*)&S.w.a.nfs[c][ib];
                    float4 n0 = np4[0], n1 = np4[1];
                    acc[0] += wc * n0.x; acc[1] += wc * n0.y; acc[2] += wc * n0.z; acc[3] += wc * n0.w;
                    acc[4] += wc * n1.x; acc[5] += wc * n1.y; acc[6] += wc * n1.z; acc[7] += wc * n1.w;
                }
            }
            float4 r0 = { fmaxf(acc[0], 0.0f), fmaxf(acc[1], 0.0f), fmaxf(acc[2], 0.0f), fmaxf(acc[3], 0.0f) };
            float4 r1 = { fmaxf(acc[4], 0.0f), fmaxf(acc[5], 0.0f), fmaxf(acc[6], 0.0f), fmaxf(acc[7], 0.0f) };
            *(float4*)&S.w.a.h1s[o][ib]     = r0;
            *(float4*)&S.w.a.h1s[o][ib + 4] = r1;
        }
        __syncthreads();

        // MLP layer 2: 64 -> 64 (packed w2p)
        {
            const int o = t & 63, ib = (t >> 6) << 3;
            float acc[8];
            float bb = b2[o];
#pragma unroll
            for (int k = 0; k < 8; ++k) acc[k] = bb;
            const float4* wp = (const float4*)w2p;
#pragma unroll
            for (int c4 = 0; c4 < 16; ++c4) {
                float4 w = wp[c4 * 64 + o];
#pragma unroll
                for (int cl = 0; cl < 4; ++cl) {
                    const int c = 4 * c4 + cl;
                    float wc = ((const float*)&w)[cl];
                    const float4* hp4 = (const float4*)&S.w.a.h1s[c][ib];
                    float4 h0 = hp4[0], h1v = hp4[1];
                    acc[0] += wc * h0.x; acc[1] += wc * h0.y; acc[2] += wc * h0.z; acc[3] += wc * h0.w;
                    acc[4] += wc * h1v.x; acc[5] += wc * h1v.y; acc[6] += wc * h1v.z; acc[7] += wc * h1v.w;
                }
            }
            float4 r0 = { fmaxf(acc[0], 0.0f), fmaxf(acc[1], 0.0f), fmaxf(acc[2], 0.0f), fmaxf(acc[3], 0.0f) };
            float4 r1 = { fmaxf(acc[4], 0.0f), fmaxf(acc[5], 0.0f), fmaxf(acc[6], 0.0f), fmaxf(acc[7], 0.0f) };
            *(float4*)&S.w.a.h2s[o][ib]     = r0;
            *(float4*)&S.w.a.h2s[o][ib + 4] = r1;
        }
        __syncthreads();

        // MLP layer 3: 64 -> 128 (packed w3p), relu, maxpool over M
        {
            const int o = t & 127, ib = (t >> 7) << 4;
            float acc[16];
            float bb = b3[o];
#pragma unroll
            for (int k = 0; k < 16; ++k) acc[k] = bb;
            const float4* wp = (const float4*)w3p;
#pragma unroll
            for (int c4 = 0; c4 < 16; ++c4) {
                float4 w = wp[c4 * 128 + o];
#pragma unroll
                for (int cl = 0; cl < 4; ++cl) {
                    const int c = 4 * c4 + cl;
                    float wc = ((const float*)&w)[cl];
                    const float4* hp4 = (const float4*)&S.w.a.h2s[c][ib];
                    float4 h0 = hp4[0], h1v = hp4[1], h2v = hp4[2], h3v = hp4[3];
                    acc[0]  += wc * h0.x;  acc[1]  += wc * h0.y;  acc[2]  += wc * h0.z;  acc[3]  += wc * h0.w;
                    acc[4]  += wc * h1v.x; acc[5]  += wc * h1v.y; acc[6]  += wc * h1v.z; acc[7]  += wc * h1v.w;
                    acc[8]  += wc * h2v.x; acc[9]  += wc * h2v.y; acc[10] += wc * h2v.z; acc[11] += wc * h2v.w;
                    acc[12] += wc * h3v.x; acc[13] += wc * h3v.y; acc[14] += wc * h3v.z; acc[15] += wc * h3v.w;
                }
            }
            float mx = -1e30f;
#pragma unroll
            for (int k = 0; k < 16; ++k) mx = fmaxf(mx, fmaxf(acc[k], 0.0f));
            S.w.a.pmax[o][t >> 7] = mx;
        }
        __syncthreads();

        if (t < 128) {
            float v = fmaxf(S.w.a.pmax[t][0], S.w.a.pmax[t][1]);
            out[(b * 128 + t) * NP + p] = v;
        }
        __syncthreads();   // LDS reuse safe for next pair
    }
}

extern "C" void kernel_launch(void* const* d_in, const int* in_sizes, int n_in,
                              void* d_out, int out_size, void* d_ws, size_t ws_size,
                              hipStream_t stream)
{
    const float* xyz  = (const float*)d_in[0];
    const float* feat = (const float*)d_in[1];
    const float* aw1  = (const float*)d_in[2];
    const float* ab1  = (const float*)d_in[3];
    const float* aw2  = (const float*)d_in[4];
    const float* ab2  = (const float*)d_in[5];
    const float* aww  = (const float*)d_in[6];
    const float* abw  = (const float*)d_in[7];
    const float* mw1  = (const float*)d_in[8];
    const float* mb1  = (const float*)d_in[9];
    const float* mw2  = (const float*)d_in[10];
    const float* mb2  = (const float*)d_in[11];
    const float* mw3  = (const float*)d_in[12];
    const float* mb3  = (const float*)d_in[13];

    float* out    = (float*)d_out;
    float* newxyz = out;                  // (B, NP, 3) = 6144 floats
    float* out2   = out + BB * NP * 3;    // (B, 128, NP)

    float* w1p = (float*)d_ws;            // [9][64][4]
    float* w2p = w1p + 9 * 64 * 4;        // [16][64][4]
    float* w3p = w2p + 16 * 64 * 4;       // [16][128][4]
    int* progress = (int*)(w3p + 16 * 128 * 4);

    prep_kernel<<<dim3(8), dim3(256), 0, stream>>>(mw1, mw2, mw3, w1p, w2p, w3p, progress);

    mega_kernel<<<dim3(WGRID), dim3(256), 0, stream>>>(
        xyz, feat, newxyz,
        aw1, ab1, aw2, ab2, aww, abw,
        w1p, mb1, w2p, mb2, w3p, mb3, out2, progress);
}

// Round 18
// 790.980 us; speedup vs baseline: 1.0071x; 1.0071x over previous
//
#include <hip/hip_runtime.h>

#define BB 2
#define NN 4096
#define NP 1024
#define MM 32
#define CC 35
#define CIN 32
#define WGRID 256   // 2 producers + 254 workers; 1 block/CU

typedef float f2 __attribute__((ext_vector_type(2)));

// key-only DPP max-combine (u64 key = dist_bits<<32 | ~idx)
#define KEY_DPP(CTRL) do { \
    int _lo = (int)(unsigned)key, _hi = (int)(unsigned)(key >> 32); \
    int _olo = __builtin_amdgcn_mov_dpp(_lo, CTRL, 0xF, 0xF, true); \
    int _ohi = __builtin_amdgcn_mov_dpp(_hi, CTRL, 0xF, 0xF, true); \
    unsigned long long _ok = ((unsigned long long)(unsigned)_ohi << 32) | (unsigned)_olo; \
    if (_ok > key) key = _ok; \
} while (0)

// ---------------- prep: zero progress + pack MLP weights [c4][o][4] ----------------
__global__ void prep_kernel(const float* __restrict__ w1, const float* __restrict__ w2,
                            const float* __restrict__ w3,
                            float* __restrict__ w1p, float* __restrict__ w2p,
                            float* __restrict__ w3p, int* __restrict__ progress)
{
    int g = blockIdx.x * 256 + threadIdx.x;
    int stride = gridDim.x * 256;
    if (g < 2) progress[g] = 0;
    for (int i = g; i < 9 * 64 * 4; i += stride) {
        int c4 = i >> 8, o = (i >> 2) & 63, cl = i & 3;
        int c = 4 * c4 + cl;
        w1p[i] = (c < CC) ? w1[o * CC + c] : 0.0f;
    }
    for (int i = g; i < 16 * 64 * 4; i += stride) {
        int c4 = i >> 8, o = (i >> 2) & 63, cl = i & 3;
        w2p[i] = w2[o * 64 + 4 * c4 + cl];
    }
    for (int i = g; i < 16 * 128 * 4; i += stride) {
        int c4 = i >> 9, o = (i >> 2) & 127, cl = i & 3;
        w3p[i] = w3[o * 64 + 4 * c4 + cl];
    }
}

// ---------------- mega: fps producers (blocks 0..1) + knnafa workers ----------------
// Producer publishes via LDS staging + chunked sc1 flush with DEFERRED flag:
// at end of chunk k, t0 release-publishes chunk k-1's flag (zero outstanding
// vmem at that point -> free), THEN lanes t<48 flush chunk k (ack hides under
// the next 16 steps). MALL latency never lands on the fps serial chain --
// the R16/R17 regression (563->800) was the per-step sc1 store ack drained
// at every __syncthreads.
union MegaSmem {
    struct {
        float4 pc[NN];                         // coord table for far-lookup (64KB)
        float nxs[NP * 3];                     // newxyz staging (12KB)
        unsigned long long red[2][16];         // double-buffered row winners
    } f;                                       // ~78KB, 1 block/CU
    struct {
        union {
            struct {
                unsigned kxs[NN];
                int hist[256];
                int wsum[4];
                unsigned long long blist[512];
            } k;
            struct {
                float xs_t[MM][36];
                float u[MM][20];
                float nfs[CC + 1][MM];
                float h1s[64][36];
                float h2s[64][36];
                float pmax[128][2];
            } a;
        };
        int idxs[MM];
        int scal[4];
        float qs[3];                           // this pair's newxyz (agent-coherent copy)
    } w;
};

__launch_bounds__(256, 2)
__global__ void mega_kernel(const float* __restrict__ xyz, const float* __restrict__ feat,
                            float* __restrict__ newxyz,
                            const float* __restrict__ aw1, const float* __restrict__ ab1,
                            const float* __restrict__ aw2, const float* __restrict__ ab2,
                            const float* __restrict__ aww, const float* __restrict__ abw,
                            const float* __restrict__ w1p, const float* __restrict__ b1,
                            const float* __restrict__ w2p, const float* __restrict__ b2,
                            const float* __restrict__ w3p, const float* __restrict__ b3,
                            float* __restrict__ out, int* __restrict__ progress)
{
    __shared__ MegaSmem S;
    const int t = threadIdx.x;

    if (blockIdx.x < BB) {
        // ================= FPS producer (frozen R12 loop) =================
#pragma clang fp contract(off)
        const int b = blockIdx.x;
        const float* xb = xyz + b * NN * 3;

        f2 px[8], py[8], pz[8], dist[8];
#pragma unroll
        for (int k = 0; k < 16; ++k) {
            int n = t + 256 * k;
            float x = xb[n * 3 + 0];
            float y = xb[n * 3 + 1];
            float z = xb[n * 3 + 2];
            px[k >> 1][k & 1] = x;
            py[k >> 1][k & 1] = y;
            pz[k >> 1][k & 1] = z;
            dist[k >> 1][k & 1] = 1e10f;
            S.f.pc[n] = make_float4(x, y, z, 0.0f);
        }
        __syncthreads();

        int far = 0;
        for (int s = 0; s < NP; ++s) {
            float4 c = S.f.pc[far];            // uniform LDS broadcast
            if (t == 0) {                      // cheap LDS staging
                S.f.nxs[s * 3 + 0] = c.x;
                S.f.nxs[s * 3 + 1] = c.y;
                S.f.nxs[s * 3 + 2] = c.z;
            }
            const f2 cx = { c.x, c.x }, cy = { c.y, c.y }, cz = { c.z, c.z };

            float bv = -1.0f; int bi = 0;
#pragma unroll
            for (int j = 0; j < 8; ++j) {
                f2 dx = px[j] - cx, dy = py[j] - cy, dz = pz[j] - cz;
                f2 d = (dx * dx + dy * dy) + dz * dz;
                f2 dd = __builtin_elementwise_min(dist[j], d);
                dist[j] = dd;
                if (dd.x > bv) { bv = dd.x; bi = t + 256 * (2 * j); }
                if (dd.y > bv) { bv = dd.y; bi = t + 256 * (2 * j + 1); }
            }

            unsigned long long key =
                ((unsigned long long)(unsigned)__float_as_int(bv) << 32)
                | (unsigned)(0xFFFFFFFFu - (unsigned)bi);

            KEY_DPP(0xB1);
            KEY_DPP(0x4E);
            KEY_DPP(0x141);
            KEY_DPP(0x140);

            const int buf = s & 1;
            if ((t & 15) == 0) S.f.red[buf][t >> 4] = key;
            __syncthreads();

            key = S.f.red[buf][t & 15];
            KEY_DPP(0xB1);
            KEY_DPP(0x4E);
            KEY_DPP(0x141);
            KEY_DPP(0x140);
            far = (int)(0xFFFFFFFFu - (unsigned)key);

            if ((s & 15) == 15) {
                // 1) flag for the PREVIOUS chunk (its flush settled 16 steps
                //    ago -> release's vmcnt wait is free)
                if (t == 0 && s >= 31)
                    __hip_atomic_store(&progress[b], s + 1 - 16, __ATOMIC_RELEASE,
                                       __HIP_MEMORY_SCOPE_AGENT);
                // 2) flush THIS chunk (fire-and-forget; ack hides under the
                //    next 16 steps of compute)
                int fb = (s - 15) * 3;
                if (t < 48)
                    __hip_atomic_store(&newxyz[b * NP * 3 + fb + t], S.f.nxs[fb + t],
                                       __ATOMIC_RELAXED, __HIP_MEMORY_SCOPE_AGENT);
            }
        }
        // final: last chunk already flushed at s=1023; release everything
        if (t == 0)
            __hip_atomic_store(&progress[b], NP, __ATOMIC_RELEASE,
                               __HIP_MEMORY_SCOPE_AGENT);
        return;
    }

    // ================= workers: grid-stride over (b,p) pairs =================
    for (int pair = blockIdx.x - BB; pair < BB * NP; pair += WGRID - BB) {
        const int p = pair >> 1, b = pair & 1;
        const int bp = b * NP + p;

        // wait until fps has published+flushed newxyz[b][p]; fetch coherently
        if (t == 0) {
            while (__hip_atomic_load(&progress[b], __ATOMIC_RELAXED,
                                     __HIP_MEMORY_SCOPE_AGENT) <= p)
                __builtin_amdgcn_s_sleep(127);
            (void)__hip_atomic_load(&progress[b], __ATOMIC_ACQUIRE,
                                    __HIP_MEMORY_SCOPE_AGENT);
            S.w.qs[0] = __hip_atomic_load(&newxyz[bp * 3 + 0], __ATOMIC_RELAXED,
                                          __HIP_MEMORY_SCOPE_AGENT);
            S.w.qs[1] = __hip_atomic_load(&newxyz[bp * 3 + 1], __ATOMIC_RELAXED,
                                          __HIP_MEMORY_SCOPE_AGENT);
            S.w.qs[2] = __hip_atomic_load(&newxyz[bp * 3 + 2], __ATOMIC_RELAXED,
                                          __HIP_MEMORY_SCOPE_AGENT);
        }
        __syncthreads();

        // ---- kNN phase (radix-select; exact: contract off) ----
        {
#pragma clang fp contract(off)
            const float* xb = xyz + b * NN * 3;
            const float qx = S.w.qs[0];
            const float qy = S.w.qs[1];
            const float qz = S.w.qs[2];
            const float qn = (qx * qx + qy * qy) + qz * qz;

            S.w.k.hist[t] = 0;
            if (t < 4) S.w.scal[t] = 0;
            __syncthreads();

#pragma unroll
            for (int k = 0; k < 16; ++k) {
                int n = t + 256 * k;
                float x = xb[n * 3 + 0], y = xb[n * 3 + 1], z = xb[n * 3 + 2];
                float xn = (x * x + y * y) + z * z;
                float dt = (qx * x + qy * y) + qz * z;
                float d = (qn + xn) - 2.0f * dt;
                unsigned bits = __float_as_uint(d);
                unsigned kx = bits ^ ((unsigned)((int)bits >> 31) | 0x80000000u);
                S.w.k.kxs[n] = kx;
                atomicAdd(&S.w.k.hist[kx >> 24], 1);
            }
            __syncthreads();

            {   // prefix over 256 buckets; locate boundary bucket
                int c = S.w.k.hist[t];
                int incl = c;
                const int lane = t & 63, w = t >> 6;
#pragma unroll
                for (int off = 1; off < 64; off <<= 1) {
                    int o = __shfl_up(incl, off);
                    if (lane >= off) incl += o;
                }
                if (lane == 63) S.w.k.wsum[w] = incl;
                __syncthreads();
                int base = 0;
                for (int ww = 0; ww < 4; ++ww) if (ww < w) base += S.w.k.wsum[ww];
                int excl = base + incl - c;
                if (excl < MM && MM <= excl + c) { S.w.scal[0] = t; S.w.scal[1] = excl; }
            }
            __syncthreads();

            const int B = S.w.scal[0];
            const int cntBelow = S.w.scal[1];
            const unsigned bstart = (unsigned)B << 24;

#pragma unroll
            for (int k = 0; k < 16; ++k) {
                int n = t + 256 * k;
                unsigned kx = S.w.k.kxs[n];
                if (kx < bstart) {
                    int pos = atomicAdd(&S.w.scal[3], 1);
                    S.w.idxs[pos] = n;
                } else if ((kx >> 24) == (unsigned)B) {
                    int pos = atomicAdd(&S.w.scal[2], 1);
                    if (pos < 512) S.w.k.blist[pos] = ((unsigned long long)kx << 32) | (unsigned)n;
                }
            }
            __syncthreads();

            const int nB = S.w.scal[2];
            const int k2 = MM - cntBelow;

            if (nB <= 512) {
                for (int m = t; m < nB; m += 256) {
                    unsigned long long my = S.w.k.blist[m];
                    int rank = 0;
                    for (int q = 0; q < nB; ++q) rank += (S.w.k.blist[q] < my) ? 1 : 0;
                    if (rank < k2)
                        S.w.idxs[cntBelow + rank] = (int)(my & 0xFFFFFFFFu);
                }
            } else {
                for (int r = 0; r < MM; ++r) {
                    unsigned bvk = 0xFFFFFFFFu; int bi = NN;
#pragma unroll
                    for (int k = 0; k < 16; ++k) {
                        int n = t + 256 * k;
                        unsigned v = S.w.k.kxs[n];
                        if (v < bvk) { bvk = v; bi = n; }
                    }
#pragma unroll
                    for (int off = 1; off < 64; off <<= 1) {
                        unsigned ov = __shfl_xor(bvk, off);
                        int   oi = __shfl_xor(bi, off);
                        if (ov < bvk || (ov == bvk && oi < bi)) { bvk = ov; bi = oi; }
                    }
                    if ((t & 63) == 0) { S.w.k.hist[t >> 6] = (int)bvk; S.w.k.wsum[t >> 6] = bi; }
                    __syncthreads();
                    unsigned fv = (unsigned)S.w.k.hist[0]; int fi = S.w.k.wsum[0];
#pragma unroll
                    for (int w = 1; w < 4; ++w) {
                        unsigned ov = (unsigned)S.w.k.hist[w]; int oi = S.w.k.wsum[w];
                        if (ov < fv || (ov == fv && oi < fi)) { fv = ov; fi = oi; }
                    }
                    if (t == 0) { S.w.idxs[r] = fi; S.w.k.kxs[fi] = 0xFFFFFFFFu; }
                    __syncthreads();
                }
            }
        }
        __syncthreads();   // knn buffers dead; afa buffers live

        // ---- gather x = concat(gxyz, gfeat) as [m][c] ----
        {
            const int m = t & 31, c0 = t >> 5;
            const int id = S.w.idxs[m] & (NN - 1);
            for (int c = c0; c < CC; c += 8) {
                float v;
                if (c < 3) v = xyz[(b * NN + id) * 3 + c] - S.w.qs[c];
                else       v = feat[(b * CIN + (c - 3)) * NN + id];
                S.w.a.xs_t[m][c] = v;
            }
            if (c0 == 0) S.w.a.xs_t[m][35] = 0.0f;
        }
        __syncthreads();

        const int i = t >> 3, jg = t & 7;

        float xi[36];
        {
            const float4* xp = (const float4*)&S.w.a.xs_t[i][0];
#pragma unroll
            for (int q = 0; q < 9; ++q) {
                float4 v = xp[q];
                xi[4 * q] = v.x; xi[4 * q + 1] = v.y; xi[4 * q + 2] = v.z; xi[4 * q + 3] = v.w;
            }
        }

        // phase A (u-split): thread (i,jg) computes o = 2jg, 2jg+1
#pragma unroll
        for (int oo = 0; oo < 2; ++oo) {
            const int o = 2 * jg + oo;
            float acc = 0.0f;
#pragma unroll
            for (int c = 0; c < CC; ++c) acc += aw1[o * CC + c] * xi[c];
            S.w.a.u[i][o] = acc;
        }
        __syncthreads();

        float ui[16];
        {
            const float4* up = (const float4*)&S.w.a.u[i][0];
#pragma unroll
            for (int q = 0; q < 4; ++q) {
                float4 v = up[q];
                ui[4 * q] = v.x; ui[4 * q + 1] = v.y; ui[4 * q + 2] = v.z; ui[4 * q + 3] = v.w;
            }
        }

        // phase B: per pair (i, j = jg+8*jk)
        float afa[CC];
#pragma unroll
        for (int c = 0; c < CC; ++c) afa[c] = 0.0f;

#pragma unroll
        for (int jk = 0; jk < 4; ++jk) {
            const int j = jg + 8 * jk;
            const bool diag = (i == j);

            float uj[16];
            {
                const float4* up = (const float4*)&S.w.a.u[j][0];
#pragma unroll
                for (int q = 0; q < 4; ++q) {
                    float4 v = up[q];
                    uj[4 * q] = v.x; uj[4 * q + 1] = v.y; uj[4 * q + 2] = v.z; uj[4 * q + 3] = v.w;
                }
            }

            float h1[16];
#pragma unroll
            for (int o = 0; o < 16; ++o) {
                float sv = ui[o] - uj[o];
                if (diag) sv += ui[o];
                h1[o] = fmaxf(sv + ab1[o], 0.0f);
            }

            float xj[36];
            {
                const float4* xp = (const float4*)&S.w.a.xs_t[j][0];
#pragma unroll
                for (int q = 0; q < 9; ++q) {
                    float4 v = xp[q];
                    xj[4 * q] = v.x; xj[4 * q + 1] = v.y; xj[4 * q + 2] = v.z; xj[4 * q + 3] = v.w;
                }
            }

            float h2[16];
#pragma unroll
            for (int o = 0; o < 16; ++o) {
                float acc = ab2[o];
#pragma unroll
                for (int c = 0; c < 16; ++c) acc += aw2[o * 16 + c] * h1[c];
                h2[o] = fmaxf(acc, 0.0f);
            }

#pragma unroll
            for (int c = 0; c < CC; ++c) {
                float acc = abw[c];
#pragma unroll
                for (int k = 0; k < 16; ++k) acc += aww[c * 16 + k] * h2[k];
                float pc_ = xi[c] - xj[c];
                if (diag) pc_ += xi[c];
                afa[c] += pc_ * acc;
            }
        }

#pragma unroll
        for (int c = 0; c < CC; ++c) {
            float v = afa[c];
            v += __shfl_xor(v, 1);
            v += __shfl_xor(v, 2);
            v += __shfl_xor(v, 4);
            if (jg == 0) S.w.a.nfs[c][i] = xi[c] + v;
        }
        if (jg == 0) S.w.a.nfs[35][i] = 0.0f;
        __syncthreads();

        // MLP layer 1: 35 -> 64 (packed w1p; c=35 pad term exactly 0)
        {
            const int o = t & 63, ib = (t >> 6) << 3;
            float acc[8];
            float bb = b1[o];
#pragma unroll
            for (int k = 0; k < 8; ++k) acc[k] = bb;
            const float4* wp = (const float4*)w1p;
#pragma unroll
            for (int c4 = 0; c4 < 9; ++c4) {
                float4 w = wp[c4 * 64 + o];
#pragma unroll
                for (int cl = 0; cl < 4; ++cl) {
                    const int c = 4 * c4 + cl;
                    float wc = ((const float*)&w)[cl];
                    const float4* np4 = (const float4*)&S.w.a.nfs[c][ib];
                    float4 n0 = np4[0], n1 = np4[1];
                    acc[0] += wc * n0.x; acc[1] += wc * n0.y; acc[2] += wc * n0.z; acc[3] += wc * n0.w;
                    acc[4] += wc * n1.x; acc[5] += wc * n1.y; acc[6] += wc * n1.z; acc[7] += wc * n1.w;
                }
            }
            float4 r0 = { fmaxf(acc[0], 0.0f), fmaxf(acc[1], 0.0f), fmaxf(acc[2], 0.0f), fmaxf(acc[3], 0.0f) };
            float4 r1 = { fmaxf(acc[4], 0.0f), fmaxf(acc[5], 0.0f), fmaxf(acc[6], 0.0f), fmaxf(acc[7], 0.0f) };
            *(float4*)&S.w.a.h1s[o][ib]     = r0;
            *(float4*)&S.w.a.h1s[o][ib + 4] = r1;
        }
        __syncthreads();

        // MLP layer 2: 64 -> 64 (packed w2p)
        {
            const int o = t & 63, ib = (t >> 6) << 3;
            float acc[8];
            float bb = b2[o];
#pragma unroll
            for (int k = 0; k < 8; ++k) acc[k] = bb;
            const float4* wp = (const float4*)w2p;
#pragma unroll
            for (int c4 = 0; c4 < 16; ++c4) {
                float4 w = wp[c4 * 64 + o];
#pragma unroll
                for (int cl = 0; cl < 4; ++cl) {
                    const int c = 4 * c4 + cl;
                    float wc = ((const float*)&w)[cl];
                    const float4* hp4 = (const float4*)&S.w.a.h1s[c][ib];
                    float4 h0 = hp4[0], h1v = hp4[1];
                    acc[0] += wc * h0.x; acc[1] += wc * h0.y; acc[2] += wc * h0.z; acc[3] += wc * h0.w;
                    acc[4] += wc * h1v.x; acc[5] += wc * h1v.y; acc[6] += wc * h1v.z; acc[7] += wc * h1v.w;
                }
            }
            float4 r0 = { fmaxf(acc[0], 0.0f), fmaxf(acc[1], 0.0f), fmaxf(acc[2], 0.0f), fmaxf(acc[3], 0.0f) };
            float4 r1 = { fmaxf(acc[4], 0.0f), fmaxf(acc[5], 0.0f), fmaxf(acc[6], 0.0f), fmaxf(acc[7], 0.0f) };
            *(float4*)&S.w.a.h2s[o][ib]     = r0;
            *(float4*)&S.w.a.h2s[o][ib + 4] = r1;
        }
        __syncthreads();

        // MLP layer 3: 64 -> 128 (packed w3p), relu, maxpool over M
        {
            const int o = t & 127, ib = (t >> 7) << 4;
            float acc[16];
            float bb = b3[o];
#pragma unroll
            for (int k = 0; k < 16; ++k) acc[k] = bb;
            const float4* wp = (const float4*)w3p;
#pragma unroll
            for (int c4 = 0; c4 < 16; ++c4) {
                float4 w = wp[c4 * 128 + o];
#pragma unroll
                for (int cl = 0; cl < 4; ++cl) {
                    const int c = 4 * c4 + cl;
                    float wc = ((const float*)&w)[cl];
                    const float4* hp4 = (const float4*)&S.w.a.h2s[c][ib];
                    float4 h0 = hp4[0], h1v = hp4[1], h2v = hp4[2], h3v = hp4[3];
                    acc[0]  += wc * h0.x;  acc[1]  += wc * h0.y;  acc[2]  += wc * h0.z;  acc[3]  += wc * h0.w;
                    acc[4]  += wc * h1v.x; acc[5]  += wc * h1v.y; acc[6]  += wc * h1v.z; acc[7]  += wc * h1v.w;
                    acc[8]  += wc * h2v.x; acc[9]  += wc * h2v.y; acc[10] += wc * h2v.z; acc[11] += wc * h2v.w;
                    acc[12] += wc * h3v.x; acc[13] += wc * h3v.y; acc[14] += wc * h3v.z; acc[15] += wc * h3v.w;
                }
            }
            float mx = -1e30f;
#pragma unroll
            for (int k = 0; k < 16; ++k) mx = fmaxf(mx, fmaxf(acc[k], 0.0f));
            S.w.a.pmax[o][t >> 7] = mx;
        }
        __syncthreads();

        if (t < 128) {
            float v = fmaxf(S.w.a.pmax[t][0], S.w.a.pmax[t][1]);
            out[(b * 128 + t) * NP + p] = v;
        }
        __syncthreads();   // LDS reuse safe for next pair
    }
}

extern "C" void kernel_launch(void* const* d_in, const int* in_sizes, int n_in,
                              void* d_out, int out_size, void* d_ws, size_t ws_size,
                              hipStream_t stream)
{
    const float* xyz  = (const float*)d_in[0];
    const float* feat = (const float*)d_in[1];
    const float* aw1  = (const float*)d_in[2];
    const float* ab1  = (const float*)d_in[3];
    const float* aw2  = (const float*)d_in[4];
    const float* ab2  = (const float*)d_in[5];
    const float* aww  = (const float*)d_in[6];
    const float* abw  = (const float*)d_in[7];
    const float* mw1  = (const float*)d_in[8];
    const float* mb1  = (const float*)d_in[9];
    const float* mw2  = (const float*)d_in[10];
    const float* mb2  = (const float*)d_in[11];
    const float* mw3  = (const float*)d_in[12];
    const float* mb3  = (const float*)d_in[13];

    float* out    = (float*)d_out;
    float* newxyz = out;                  // (B, NP, 3) = 6144 floats
    float* out2   = out + BB * NP * 3;    // (B, 128, NP)

    float* w1p = (float*)d_ws;            // [9][64][4]
    float* w2p = w1p + 9 * 64 * 4;        // [16][64][4]
    float* w3p = w2p + 16 * 64 * 4;       // [16][128][4]
    int* progress = (int*)(w3p + 16 * 128 * 4);

    prep_kernel<<<dim3(8), dim3(256), 0, stream>>>(mw1, mw2, mw3, w1p, w2p, w3p, progress);

    mega_kernel<<<dim3(WGRID), dim3(256), 0, stream>>>(
        xyz, feat, newxyz,
        aw1, ab1, aw2, ab2, aww, abw,
        w1p, mb1, w2p, mb2, w3p, mb3, out2, progress);
}

// Round 19
// 718.564 us; speedup vs baseline: 1.1086x; 1.1008x over previous
//
#include <hip/hip_runtime.h>

#define BB 2
#define NN 4096
#define NP 1024
#define MM 32
#define CC 35
#define CIN 32

typedef float f2 __attribute__((ext_vector_type(2)));

// key-only DPP max-combine (u64 key = dist_bits<<32 | ~idx)
#define KEY_DPP(CTRL) do { \
    int _lo = (int)(unsigned)key, _hi = (int)(unsigned)(key >> 32); \
    int _olo = __builtin_amdgcn_mov_dpp(_lo, CTRL, 0xF, 0xF, true); \
    int _ohi = __builtin_amdgcn_mov_dpp(_hi, CTRL, 0xF, 0xF, true); \
    unsigned long long _ok = ((unsigned long long)(unsigned)_ohi << 32) | (unsigned)_olo; \
    if (_ok > key) key = _ok; \
} while (0)

// ---------------- FPS (blocks 0..BB-1) + packed-weight prep (blocks BB..) ----
// fps: FROZEN R12 structure (563 us measured; R14-R18 overlap line dead).
__launch_bounds__(256)
__global__ void fps_prep_kernel(const float* __restrict__ xyz, float* __restrict__ newxyz_out,
                                const float* __restrict__ w1, const float* __restrict__ w2,
                                const float* __restrict__ w3,
                                float* __restrict__ w1p, float* __restrict__ w2p,
                                float* __restrict__ w3p)
{
#pragma clang fp contract(off)
    const int t = threadIdx.x;

    if (blockIdx.x >= BB) {   // ---- prep: pack MLP weights as [c4][o][4] ----
        int g = (blockIdx.x - BB) * 256 + t;
        int stride = 8 * 256;
        for (int i = g; i < 9 * 64 * 4; i += stride) {
            int c4 = i >> 8, o = (i >> 2) & 63, cl = i & 3;
            int c = 4 * c4 + cl;
            w1p[i] = (c < CC) ? w1[o * CC + c] : 0.0f;
        }
        for (int i = g; i < 16 * 64 * 4; i += stride) {
            int c4 = i >> 8, o = (i >> 2) & 63, cl = i & 3;
            w2p[i] = w2[o * 64 + 4 * c4 + cl];
        }
        for (int i = g; i < 16 * 128 * 4; i += stride) {
            int c4 = i >> 9, o = (i >> 2) & 127, cl = i & 3;
            w3p[i] = w3[o * 64 + 4 * c4 + cl];
        }
        return;
    }

    const int b = blockIdx.x;
    const float* xb = xyz + b * NN * 3;

    __shared__ float4 pc[NN];                  // coord table for far-lookup
    __shared__ float nxs[NP * 3];              // newxyz staging
    __shared__ unsigned long long red[2][16];  // double-buffered row winners

    f2 px[8], py[8], pz[8], dist[8];
#pragma unroll
    for (int k = 0; k < 16; ++k) {
        int n = t + 256 * k;
        float x = xb[n * 3 + 0];
        float y = xb[n * 3 + 1];
        float z = xb[n * 3 + 2];
        px[k >> 1][k & 1] = x;
        py[k >> 1][k & 1] = y;
        pz[k >> 1][k & 1] = z;
        dist[k >> 1][k & 1] = 1e10f;
        pc[n] = make_float4(x, y, z, 0.0f);
    }
    __syncthreads();

    int far = 0;
    for (int s = 0; s < NP; ++s) {
        float4 c = pc[far];                    // uniform LDS broadcast
        if (t == 0) {
            nxs[s * 3 + 0] = c.x;
            nxs[s * 3 + 1] = c.y;
            nxs[s * 3 + 2] = c.z;
        }
        const f2 cx = { c.x, c.x }, cy = { c.y, c.y }, cz = { c.z, c.z };

        // packed update; scalar argmax compares (ascending order -> first-index ties)
        float bv = -1.0f; int bi = 0;
#pragma unroll
        for (int j = 0; j < 8; ++j) {
            f2 dx = px[j] - cx, dy = py[j] - cy, dz = pz[j] - cz;
            f2 d = (dx * dx + dy * dy) + dz * dz;
            f2 dd = __builtin_elementwise_min(dist[j], d);
            dist[j] = dd;
            if (dd.x > bv) { bv = dd.x; bi = t + 256 * (2 * j); }
            if (dd.y > bv) { bv = dd.y; bi = t + 256 * (2 * j + 1); }
        }

        unsigned long long key =
            ((unsigned long long)(unsigned)__float_as_int(bv) << 32)
            | (unsigned)(0xFFFFFFFFu - (unsigned)bi);

        KEY_DPP(0xB1);   // xor 1
        KEY_DPP(0x4E);   // xor 2
        KEY_DPP(0x141);  // cross-quad combine
        KEY_DPP(0x140);  // cross-octet -> row of 16 converged

        const int buf = s & 1;
        if ((t & 15) == 0) red[buf][t >> 4] = key;
        __syncthreads();

        key = red[buf][t & 15];
        KEY_DPP(0xB1);
        KEY_DPP(0x4E);
        KEY_DPP(0x141);
        KEY_DPP(0x140);
        far = (int)(0xFFFFFFFFu - (unsigned)key);
    }

    __syncthreads();
#pragma unroll
    for (int j = 0; j < 12; ++j) {
        int i = t + 256 * j;
        newxyz_out[b * NP * 3 + i] = nxs[i];
    }
}

// ---------------- fused radix-kNN + gather + AFA + MLP + maxpool ----------------
// R13 structure (716 us measured). Single change vs R13: kNN distance pass
// loads xyz as 3x float4 per thread-group-of-4-consecutive-points (48B
// coalesced, 16B-aligned) instead of 12 scalar loads -- selection is
// order-independent (histogram + exact rank-select), so the new coverage
// order n = 4t+j+1024k is semantically neutral.
__launch_bounds__(256)
__global__ void knnafa_kernel(const float* __restrict__ xyz, const float* __restrict__ feat,
                              const float* __restrict__ newxyz,
                              const float* __restrict__ aw1, const float* __restrict__ ab1,
                              const float* __restrict__ aw2, const float* __restrict__ ab2,
                              const float* __restrict__ aww, const float* __restrict__ abw,
                              const float* __restrict__ w1p, const float* __restrict__ b1,
                              const float* __restrict__ w2p, const float* __restrict__ b2,
                              const float* __restrict__ w3p, const float* __restrict__ b3,
                              float* __restrict__ out)
{
    const int bp = blockIdx.x;
    const int b = bp >> 10, p = bp & 1023;
    const int t = threadIdx.x;

    union Smem {
        struct {
            unsigned kxs[NN];                  // 16KB sortable keys
            int hist[256];
            int wsum[4];
            unsigned long long blist[512];     // boundary-bucket members
        } k;
        struct {
            float xs_t[MM][36];
            float u[MM][20];
            float nfs[CC + 1][MM];             // row 35 zeroed (pad for packed w1)
            float h1s[64][36];
            float h2s[64][36];
            float pmax[128][2];
        } a;
    };
    __shared__ Smem S;
    __shared__ int idxs[MM];
    __shared__ int scal[4];                    // [0]=B [1]=cntBelow [2]=nB [3]=outcnt

    // ================= kNN phase (exact: contract off) =================
    {
#pragma clang fp contract(off)
        const float* xb = xyz + b * NN * 3;
        const float qx = newxyz[bp * 3 + 0];
        const float qy = newxyz[bp * 3 + 1];
        const float qz = newxyz[bp * 3 + 2];
        const float qn = (qx * qx + qy * qy) + qz * qz;

        S.k.hist[t] = 0;
        if (t < 4) scal[t] = 0;
        __syncthreads();

        // vectorized: thread t covers points n0 = 4*(t+256*k2) .. n0+3 via 3 float4
#pragma unroll
        for (int k2 = 0; k2 < 4; ++k2) {
            const int n0 = 4 * (t + 256 * k2);
            const float4* xp = (const float4*)&xb[n0 * 3];
            float4 v0 = xp[0], v1 = xp[1], v2 = xp[2];
            float pxl[4] = { v0.x, v0.w, v1.z, v2.y };
            float pyl[4] = { v0.y, v1.x, v1.w, v2.z };
            float pzl[4] = { v0.z, v1.y, v2.x, v2.w };
#pragma unroll
            for (int j = 0; j < 4; ++j) {
                float x = pxl[j], y = pyl[j], z = pzl[j];
                float xn = (x * x + y * y) + z * z;
                float dt = (qx * x + qy * y) + qz * z;
                float d = (qn + xn) - 2.0f * dt;
                unsigned bits = __float_as_uint(d);
                unsigned kx = bits ^ ((unsigned)((int)bits >> 31) | 0x80000000u);
                S.k.kxs[n0 + j] = kx;
                atomicAdd(&S.k.hist[kx >> 24], 1);
            }
        }
        __syncthreads();

        {   // prefix over 256 buckets; locate boundary bucket
            int c = S.k.hist[t];
            int incl = c;
            const int lane = t & 63, w = t >> 6;
#pragma unroll
            for (int off = 1; off < 64; off <<= 1) {
                int o = __shfl_up(incl, off);
                if (lane >= off) incl += o;
            }
            if (lane == 63) S.k.wsum[w] = incl;
            __syncthreads();
            int base = 0;
            for (int ww = 0; ww < 4; ++ww) if (ww < w) base += S.k.wsum[ww];
            int excl = base + incl - c;
            if (excl < MM && MM <= excl + c) { scal[0] = t; scal[1] = excl; }
        }
        __syncthreads();

        const int B = scal[0];
        const int cntBelow = scal[1];
        const unsigned bstart = (unsigned)B << 24;

#pragma unroll
        for (int k = 0; k < 16; ++k) {
            int n = t + 256 * k;
            unsigned kx = S.k.kxs[n];
            if (kx < bstart) {
                int pos = atomicAdd(&scal[3], 1);
                idxs[pos] = n;
            } else if ((kx >> 24) == (unsigned)B) {
                int pos = atomicAdd(&scal[2], 1);
                if (pos < 512) S.k.blist[pos] = ((unsigned long long)kx << 32) | (unsigned)n;
            }
        }
        __syncthreads();

        const int nB = scal[2];
        const int k2sel = MM - cntBelow;

        if (nB <= 512) {
            for (int m = t; m < nB; m += 256) {
                unsigned long long my = S.k.blist[m];
                int rank = 0;
                for (int q = 0; q < nB; ++q) rank += (S.k.blist[q] < my) ? 1 : 0;
                if (rank < k2sel)
                    idxs[cntBelow + rank] = (int)(my & 0xFFFFFFFFu);
            }
        } else {
            // fallback (pathological duplicates): serial exact selection
            for (int r = 0; r < MM; ++r) {
                unsigned bvk = 0xFFFFFFFFu; int bi = NN;
#pragma unroll
                for (int k = 0; k < 16; ++k) {
                    int n = t + 256 * k;
                    unsigned v = S.k.kxs[n];
                    if (v < bvk) { bvk = v; bi = n; }
                }
#pragma unroll
                for (int off = 1; off < 64; off <<= 1) {
                    unsigned ov = __shfl_xor(bvk, off);
                    int   oi = __shfl_xor(bi, off);
                    if (ov < bvk || (ov == bvk && oi < bi)) { bvk = ov; bi = oi; }
                }
                if ((t & 63) == 0) { S.k.hist[t >> 6] = (int)bvk; S.k.wsum[t >> 6] = bi; }
                __syncthreads();
                unsigned fv = (unsigned)S.k.hist[0]; int fi = S.k.wsum[0];
#pragma unroll
                for (int w = 1; w < 4; ++w) {
                    unsigned ov = (unsigned)S.k.hist[w]; int oi = S.k.wsum[w];
                    if (ov < fv || (ov == fv && oi < fi)) { fv = ov; fi = oi; }
                }
                if (t == 0) { idxs[r] = fi; S.k.kxs[fi] = 0xFFFFFFFFu; }
                __syncthreads();
            }
        }
    }
    __syncthreads();   // knn buffers dead; afa buffers live from here

    // ================= gather x = concat(gxyz, gfeat) as [m][c] =================
    {
        const int m = t & 31, c0 = t >> 5;
        const int id = idxs[m] & (NN - 1);
        for (int c = c0; c < CC; c += 8) {
            float v;
            if (c < 3) v = xyz[(b * NN + id) * 3 + c] - newxyz[bp * 3 + c];
            else       v = feat[(b * CIN + (c - 3)) * NN + id];
            S.a.xs_t[m][c] = v;
        }
        if (c0 == 0) S.a.xs_t[m][35] = 0.0f;
    }
    __syncthreads();

    const int i = t >> 3, jg = t & 7;

    float xi[36];
    {
        const float4* xp = (const float4*)&S.a.xs_t[i][0];
#pragma unroll
        for (int q = 0; q < 9; ++q) {
            float4 v = xp[q];
            xi[4 * q] = v.x; xi[4 * q + 1] = v.y; xi[4 * q + 2] = v.z; xi[4 * q + 3] = v.w;
        }
    }

    // ---- phase A (u-split): thread (i,jg) computes o = 2jg, 2jg+1 only
#pragma unroll
    for (int oo = 0; oo < 2; ++oo) {
        const int o = 2 * jg + oo;
        float acc = 0.0f;
#pragma unroll
        for (int c = 0; c < CC; ++c) acc += aw1[o * CC + c] * xi[c];
        S.a.u[i][o] = acc;
    }
    __syncthreads();

    float ui[16];
    {
        const float4* up = (const float4*)&S.a.u[i][0];
#pragma unroll
        for (int q = 0; q < 4; ++q) {
            float4 v = up[q];
            ui[4 * q] = v.x; ui[4 * q + 1] = v.y; ui[4 * q + 2] = v.z; ui[4 * q + 3] = v.w;
        }
    }

    // ---- phase B: per pair (i, j = jg+8*jk)
    float afa[CC];
#pragma unroll
    for (int c = 0; c < CC; ++c) afa[c] = 0.0f;

#pragma unroll
    for (int jk = 0; jk < 4; ++jk) {
        const int j = jg + 8 * jk;
        const bool diag = (i == j);

        float uj[16];
        {
            const float4* up = (const float4*)&S.a.u[j][0];
#pragma unroll
            for (int q = 0; q < 4; ++q) {
                float4 v = up[q];
                uj[4 * q] = v.x; uj[4 * q + 1] = v.y; uj[4 * q + 2] = v.z; uj[4 * q + 3] = v.w;
            }
        }

        float h1[16];
#pragma unroll
        for (int o = 0; o < 16; ++o) {
            float sv = ui[o] - uj[o];
            if (diag) sv += ui[o];
            h1[o] = fmaxf(sv + ab1[o], 0.0f);
        }

        float xj[36];
        {
            const float4* xp = (const float4*)&S.a.xs_t[j][0];
#pragma unroll
            for (int q = 0; q < 9; ++q) {
                float4 v = xp[q];
                xj[4 * q] = v.x; xj[4 * q + 1] = v.y; xj[4 * q + 2] = v.z; xj[4 * q + 3] = v.w;
            }
        }

        float h2[16];
#pragma unroll
        for (int o = 0; o < 16; ++o) {
            float acc = ab2[o];
#pragma unroll
            for (int c = 0; c < 16; ++c) acc += aw2[o * 16 + c] * h1[c];
            h2[o] = fmaxf(acc, 0.0f);
        }

#pragma unroll
        for (int c = 0; c < CC; ++c) {
            float acc = abw[c];
#pragma unroll
            for (int k = 0; k < 16; ++k) acc += aww[c * 16 + k] * h2[k];
            float pc_ = xi[c] - xj[c];
            if (diag) pc_ += xi[c];
            afa[c] += pc_ * acc;
        }
    }

    // reduce afa across 8 lanes sharing i; nf = x + afa as [c][m]; zero pad row
#pragma unroll
    for (int c = 0; c < CC; ++c) {
        float v = afa[c];
        v += __shfl_xor(v, 1);
        v += __shfl_xor(v, 2);
        v += __shfl_xor(v, 4);
        if (jg == 0) S.a.nfs[c][i] = xi[c] + v;
    }
    if (jg == 0) S.a.nfs[35][i] = 0.0f;
    __syncthreads();

    // ---- MLP layer 1: 35 -> 64 (packed w1p [9][64][4]; c=35 pad term is exactly 0)
    {
        const int o = t & 63, ib = (t >> 6) << 3;
        float acc[8];
        float bb = b1[o];
#pragma unroll
        for (int k = 0; k < 8; ++k) acc[k] = bb;
        const float4* wp = (const float4*)w1p;
#pragma unroll
        for (int c4 = 0; c4 < 9; ++c4) {
            float4 w = wp[c4 * 64 + o];
#pragma unroll
            for (int cl = 0; cl < 4; ++cl) {
                const int c = 4 * c4 + cl;
                float wc = ((const float*)&w)[cl];
                const float4* np4 = (const float4*)&S.a.nfs[c][ib];
                float4 n0 = np4[0], n1 = np4[1];
                acc[0] += wc * n0.x; acc[1] += wc * n0.y; acc[2] += wc * n0.z; acc[3] += wc * n0.w;
                acc[4] += wc * n1.x; acc[5] += wc * n1.y; acc[6] += wc * n1.z; acc[7] += wc * n1.w;
            }
        }
        float4 r0 = { fmaxf(acc[0], 0.0f), fmaxf(acc[1], 0.0f), fmaxf(acc[2], 0.0f), fmaxf(acc[3], 0.0f) };
        float4 r1 = { fmaxf(acc[4], 0.0f), fmaxf(acc[5], 0.0f), fmaxf(acc[6], 0.0f), fmaxf(acc[7], 0.0f) };
        *(float4*)&S.a.h1s[o][ib]     = r0;
        *(float4*)&S.a.h1s[o][ib + 4] = r1;
    }
    __syncthreads();

    // ---- MLP layer 2: 64 -> 64 (packed w2p [16][64][4])
    {
        const int o = t & 63, ib = (t >> 6) << 3;
        float acc[8];
        float bb = b2[o];
#pragma unroll
        for (int k = 0; k < 8; ++k) acc[k] = bb;
        const float4* wp = (const float4*)w2p;
#pragma unroll
        for (int c4 = 0; c4 < 16; ++c4) {
            float4 w = wp[c4 * 64 + o];
#pragma unroll
            for (int cl = 0; cl < 4; ++cl) {
                const int c = 4 * c4 + cl;
                float wc = ((const float*)&w)[cl];
                const float4* hp4 = (const float4*)&S.a.h1s[c][ib];
                float4 h0 = hp4[0], h1v = hp4[1];
                acc[0] += wc * h0.x; acc[1] += wc * h0.y; acc[2] += wc * h0.z; acc[3] += wc * h0.w;
                acc[4] += wc * h1v.x; acc[5] += wc * h1v.y; acc[6] += wc * h1v.z; acc[7] += wc * h1v.w;
            }
        }
        float4 r0 = { fmaxf(acc[0], 0.0f), fmaxf(acc[1], 0.0f), fmaxf(acc[2], 0.0f), fmaxf(acc[3], 0.0f) };
        float4 r1 = { fmaxf(acc[4], 0.0f), fmaxf(acc[5], 0.0f), fmaxf(acc[6], 0.0f), fmaxf(acc[7], 0.0f) };
        *(float4*)&S.a.h2s[o][ib]     = r0;
        *(float4*)&S.a.h2s[o][ib + 4] = r1;
    }
    __syncthreads();

    // ---- MLP layer 3: 64 -> 128 (packed w3p [16][128][4]), relu, maxpool over M
    {
        const int o = t & 127, ib = (t >> 7) << 4;
        float acc[16];
        float bb = b3[o];
#pragma unroll
        for (int k = 0; k < 16; ++k) acc[k] = bb;
        const float4* wp = (const float4*)w3p;
#pragma unroll
        for (int c4 = 0; c4 < 16; ++c4) {
            float4 w = wp[c4 * 128 + o];
#pragma unroll
            for (int cl = 0; cl < 4; ++cl) {
                const int c = 4 * c4 + cl;
                float wc = ((const float*)&w)[cl];
                const float4* hp4 = (const float4*)&S.a.h2s[c][ib];
                float4 h0 = hp4[0], h1v = hp4[1], h2v = hp4[2], h3v = hp4[3];
                acc[0]  += wc * h0.x;  acc[1]  += wc * h0.y;  acc[2]  += wc * h0.z;  acc[3]  += wc * h0.w;
                acc[4]  += wc * h1v.x; acc[5]  += wc * h1v.y; acc[6]  += wc * h1v.z; acc[7]  += wc * h1v.w;
                acc[8]  += wc * h2v.x; acc[9]  += wc * h2v.y; acc[10] += wc * h2v.z; acc[11] += wc * h2v.w;
                acc[12] += wc * h3v.x; acc[13] += wc * h3v.y; acc[14] += wc * h3v.z; acc[15] += wc * h3v.w;
            }
        }
        float mx = -1e30f;
#pragma unroll
        for (int k = 0; k < 16; ++k) mx = fmaxf(mx, fmaxf(acc[k], 0.0f));
        S.a.pmax[o][t >> 7] = mx;
    }
    __syncthreads();

    if (t < 128) {
        float v = fmaxf(S.a.pmax[t][0], S.a.pmax[t][1]);
        out[(b * 128 + t) * NP + p] = v;
    }
}

extern "C" void kernel_launch(void* const* d_in, const int* in_sizes, int n_in,
                              void* d_out, int out_size, void* d_ws, size_t ws_size,
                              hipStream_t stream)
{
    const float* xyz  = (const float*)d_in[0];
    const float* feat = (const float*)d_in[1];
    const float* aw1  = (const float*)d_in[2];
    const float* ab1  = (const float*)d_in[3];
    const float* aw2  = (const float*)d_in[4];
    const float* ab2  = (const float*)d_in[5];
    const float* aww  = (const float*)d_in[6];
    const float* abw  = (const float*)d_in[7];
    const float* mw1  = (const float*)d_in[8];
    const float* mb1  = (const float*)d_in[9];
    const float* mw2  = (const float*)d_in[10];
    const float* mb2  = (const float*)d_in[11];
    const float* mw3  = (const float*)d_in[12];
    const float* mb3  = (const float*)d_in[13];

    float* out    = (float*)d_out;
    float* newxyz = out;                  // (B, NP, 3) = 6144 floats
    float* out2   = out + BB * NP * 3;    // (B, 128, NP)

    float* w1p = (float*)d_ws;            // [9][64][4]   = 2304 floats
    float* w2p = w1p + 9 * 64 * 4;        // [16][64][4]  = 4096 floats
    float* w3p = w2p + 16 * 64 * 4;       // [16][128][4] = 8192 floats

    fps_prep_kernel<<<dim3(BB + 8), dim3(256), 0, stream>>>(xyz, newxyz,
                                                            mw1, mw2, mw3, w1p, w2p, w3p);
    knnafa_kernel<<<dim3(BB * NP), dim3(256), 0, stream>>>(
        xyz, feat, newxyz,
        aw1, ab1, aw2, ab2, aww, abw,
        w1p, mb1, w2p, mb2, w3p, mb3, out2);
}